// Round 15
// baseline (233.294 us; speedup 1.0000x reference)
//
#include <hip/hip_runtime.h>

typedef unsigned short u16;
typedef __attribute__((ext_vector_type(8))) short bf16x8;
typedef __attribute__((ext_vector_type(16))) float f32x16;

#define AS1C(p) ((const __attribute__((address_space(1))) void*)(p))
#define AS3(p)  ((__attribute__((address_space(3))) void*)(p))

// s_barrier is NOT a compiler memory fence; CFENCE pins LDS/global ops.
#define CFENCE() asm volatile("" ::: "memory")

__device__ __forceinline__ u16 f2bf(float f) {
    unsigned u = __float_as_uint(f);
    u += 0x7fffu + ((u >> 16) & 1u);   // RTNE
    return (u16)(u >> 16);
}

// ---------------------------------------------------------------------------
// Fused prep: blocks [0,N): LayerNorm row -> bf16 A.
//             blocks [N,N+D): cast W_patch row -> bf16 W.
//             block  N+D:     class_emb + class_pos -> out row 0.
// Measured at HBM roofline (~48us).
// ---------------------------------------------------------------------------
__global__ __launch_bounds__(256) void prep_kernel(
    const float* __restrict__ x, const float* __restrict__ w,
    const float* __restrict__ b, const float* __restrict__ Wp,
    const float* __restrict__ ce, const float* __restrict__ cp,
    u16* __restrict__ A, u16* __restrict__ Wb, float* __restrict__ out,
    int N, int D, int K)
{
    const int blk = blockIdx.x;
    const int t = threadIdx.x;

    if (blk < N) {
        const float* xr = x + (size_t)blk * K;
        float4 v[3];
#pragma unroll
        for (int i = 0; i < 3; ++i)
            v[i] = *(const float4*)&xr[(i * 256 + t) * 4];

        float s = 0.f;
#pragma unroll
        for (int i = 0; i < 3; ++i) s += v[i].x + v[i].y + v[i].z + v[i].w;
#pragma unroll
        for (int off = 32; off; off >>= 1) s += __shfl_down(s, off);

        __shared__ float red[8];
        const int wid = t >> 6, lane = t & 63;
        if (lane == 0) red[wid] = s;
        __syncthreads();
        const float mu = (red[0] + red[1] + red[2] + red[3]) * (1.0f / 3072.0f);

        float sq = 0.f;
#pragma unroll
        for (int i = 0; i < 3; ++i) {
            float dx = v[i].x - mu, dy = v[i].y - mu, dz = v[i].z - mu, dw = v[i].w - mu;
            sq += dx * dx + dy * dy + dz * dz + dw * dw;
        }
#pragma unroll
        for (int off = 32; off; off >>= 1) sq += __shfl_down(sq, off);
        if (lane == 0) red[4 + wid] = sq;
        __syncthreads();
        const float var = (red[4] + red[5] + red[6] + red[7]) * (1.0f / 3072.0f);
        const float inv = rsqrtf(var + 1e-5f);

#pragma unroll
        for (int i = 0; i < 3; ++i) {
            const int j = (i * 256 + t) * 4;
            const float4 wv = *(const float4*)&w[j];
            const float4 bv = *(const float4*)&b[j];
            ushort4 o;
            o.x = f2bf((v[i].x - mu) * inv * wv.x + bv.x);
            o.y = f2bf((v[i].y - mu) * inv * wv.y + bv.y);
            o.z = f2bf((v[i].z - mu) * inv * wv.z + bv.z);
            o.w = f2bf((v[i].w - mu) * inv * wv.w + bv.w);
            *(ushort4*)&A[(size_t)blk * K + j] = o;
        }
    } else if (blk < N + D) {
        const int row = blk - N;
        const float* wr = Wp + (size_t)row * K;
#pragma unroll
        for (int i = 0; i < 3; ++i) {
            const int j = (i * 256 + t) * 4;
            const float4 v = *(const float4*)&wr[j];
            ushort4 o;
            o.x = f2bf(v.x); o.y = f2bf(v.y); o.z = f2bf(v.z); o.w = f2bf(v.w);
            *(ushort4*)&Wb[(size_t)row * K + j] = o;
        }
    } else {
#pragma unroll
        for (int i = 0; i < 4; ++i) {
            const int j = i * 256 + t;
            out[j] = ce[j] + cp[j];
        }
    }
}

// ---------------------------------------------------------------------------
// 256x256 bf16 GEMM, mfma_f32_32x32x16_bf16, 4 waves (2x2), wave 128x128
// (4m x 4n frags). R15: LDS-traffic-minimal register blocking —
// 8 ds_read_b128 -> 16 independent MFMA32 per k-slot (0.5 reads/MFMA).
// Per K-tile per CU: LDS 128 reads = 1536 cyc < MFMA 2066 cyc -> MFMA-bound.
// 1 wave/SIMD (acc = 256 VGPR); slot-pipelined reads 1 slot ahead with
// LGKM(8) ladder + sched_barrier(0); ONE barrier per K-tile; CFENCE;
// stage 16 gload_lds at tile start -> inactive buffer, vmcnt(0) publish at
// tile end (~free, full-tile lead). 3-bit XOR swizzle, XCD swizzle.
// ---------------------------------------------------------------------------
#define STG_A(BUFOFS, R0, T_) \
    __builtin_amdgcn_global_load_lds(AS1C(aS + (size_t)(R0) * 3072 + (T_) * 64), \
                                     AS3(dA + (BUFOFS) + (R0) * 128), 16, 0, 0)
#define STG_B(BUFOFS, R0, T_) \
    __builtin_amdgcn_global_load_lds(AS1C(bS + (size_t)(R0) * 3072 + (T_) * 64), \
                                     AS3(dB + (BUFOFS) + (R0) * 128), 16, 0, 0)

#define MFMA32(d, a, b) d = __builtin_amdgcn_mfma_f32_32x32x16_bf16(a, b, d, 0, 0, 0)

#define LGKM(N_) asm volatile("s_waitcnt lgkmcnt(" #N_ ")" ::: "memory"); \
                 __builtin_amdgcn_sched_barrier(0)

// 8 reads of one k-slot (4 A-frags, 4 B-frags).
#define RD8(BUF, CK, A0, A1, A2, A3, B0, B1, B2, B3) \
    A0 = *(const bf16x8*)(L + (BUF) + aRowBase + 0 * 4096 + (CK)); \
    A1 = *(const bf16x8*)(L + (BUF) + aRowBase + 1 * 4096 + (CK)); \
    A2 = *(const bf16x8*)(L + (BUF) + aRowBase + 2 * 4096 + (CK)); \
    A3 = *(const bf16x8*)(L + (BUF) + aRowBase + 3 * 4096 + (CK)); \
    B0 = *(const bf16x8*)(L + (BUF) + bRowBase + 0 * 4096 + (CK)); \
    B1 = *(const bf16x8*)(L + (BUF) + bRowBase + 1 * 4096 + (CK)); \
    B2 = *(const bf16x8*)(L + (BUF) + bRowBase + 2 * 4096 + (CK)); \
    B3 = *(const bf16x8*)(L + (BUF) + bRowBase + 3 * 4096 + (CK))

// 16 independent MFMA32 (4m x 4n).
#define G16(A0, A1, A2, A3, B0, B1, B2, B3) \
    MFMA32(acc[0][0], A0, B0); MFMA32(acc[1][0], A1, B0); \
    MFMA32(acc[2][0], A2, B0); MFMA32(acc[3][0], A3, B0); \
    MFMA32(acc[0][1], A0, B1); MFMA32(acc[1][1], A1, B1); \
    MFMA32(acc[2][1], A2, B1); MFMA32(acc[3][1], A3, B1); \
    MFMA32(acc[0][2], A0, B2); MFMA32(acc[1][2], A1, B2); \
    MFMA32(acc[2][2], A2, B2); MFMA32(acc[3][2], A3, B2); \
    MFMA32(acc[0][3], A0, B3); MFMA32(acc[1][3], A1, B3); \
    MFMA32(acc[2][3], A2, B3); MFMA32(acc[3][3], A3, B3)

// One K-tile: reads 1 slot ahead; LGKM(8) keeps next slot's 8 in flight.
#define TILE(BUF, STG, WT) do {                                                 \
    bf16x8 xa0, xa1, xa2, xa3, xb0, xb1, xb2, xb3;                              \
    bf16x8 ya0, ya1, ya2, ya3, yb0, yb1, yb2, yb3;                              \
    RD8(BUF, ck0, xa0, xa1, xa2, xa3, xb0, xb1, xb2, xb3);                      \
    RD8(BUF, ck1, ya0, ya1, ya2, ya3, yb0, yb1, yb2, yb3);                      \
    STG;                                                                        \
    __builtin_amdgcn_s_setprio(1);                                              \
    LGKM(8); G16(xa0, xa1, xa2, xa3, xb0, xb1, xb2, xb3);                       \
    RD8(BUF, ck2, xa0, xa1, xa2, xa3, xb0, xb1, xb2, xb3);                      \
    LGKM(8); G16(ya0, ya1, ya2, ya3, yb0, yb1, yb2, yb3);                       \
    RD8(BUF, ck3, ya0, ya1, ya2, ya3, yb0, yb1, yb2, yb3);                      \
    LGKM(8); G16(xa0, xa1, xa2, xa3, xb0, xb1, xb2, xb3);                       \
    LGKM(0); G16(ya0, ya1, ya2, ya3, yb0, yb1, yb2, yb3);                       \
    __builtin_amdgcn_s_setprio(0);                                              \
    WT;                                                                         \
    __builtin_amdgcn_s_barrier();                                               \
    CFENCE();                                                                   \
} while (0)

#define STG_ALL(OBUF, TN) \
    { STG_B(OBUF, 0, TN);   STG_B(OBUF, 32, TN);  STG_B(OBUF, 64, TN);          \
      STG_B(OBUF, 96, TN);  STG_B(OBUF, 128, TN); STG_B(OBUF, 160, TN);         \
      STG_B(OBUF, 192, TN); STG_B(OBUF, 224, TN);                               \
      STG_A(OBUF, 0, TN);   STG_A(OBUF, 32, TN);  STG_A(OBUF, 64, TN);          \
      STG_A(OBUF, 96, TN);  STG_A(OBUF, 128, TN); STG_A(OBUF, 160, TN);         \
      STG_A(OBUF, 192, TN); STG_A(OBUF, 224, TN); }

#define VMW0() asm volatile("s_waitcnt vmcnt(0)" ::: "memory")

__global__ __launch_bounds__(256, 1) void gemm_256_r15_kernel(
    const u16* __restrict__ A, const u16* __restrict__ W,
    const float* __restrict__ bbox, const float* __restrict__ Wpos,
    const float* __restrict__ bpos, float* __restrict__ out,
    int D)
{
    __shared__ __align__(16) char lds[131072];
    const char* L = (const char*)lds;
    const int K = 3072;
    const int NK = 48;                     // K / 64

    // XCD-bijective swizzle: 256 blocks, 8 XCDs, 32 contiguous tiles per XCD.
    const int bid = blockIdx.x;
    const int swb = (bid & 7) * 32 + (bid >> 3);
    const int bx = swb & 3;                // D/256 = 4
    const int by = swb >> 2;               // M/256 = 64
    const int brow = by * 256;
    const int bcol = bx * 256;

    const int t = threadIdx.x;
    const int wid = t >> 6, lane = t & 63;
    const int wm = wid >> 1;               // 0..1 (wave row)
    const int wn = wid & 1;                // 0..1 (wave col)
    const int l31 = lane & 31;
    const int klane16 = (lane >> 5) * 16;  // 16B k-half within slot
    const int xorb = (lane & 7) << 4;      // 3-bit swizzle: byte ^= (row&7)<<4
    const int aRowBase = (wm * 128 + l31) * 128;
    const int bRowBase = 32768 + (wn * 128 + l31) * 128;
    const int ck0 = (0  + klane16) ^ xorb; // k-slots 0..3 of the 64-wide K-tile
    const int ck1 = (32 + klane16) ^ xorb;
    const int ck2 = (64 + klane16) ^ xorb;
    const int ck3 = (96 + klane16) ^ xorb;

    // staging: linear LDS dest (t*16 B, 256 threads = 4KB = 32 rows), source
    // pre-swizzled: row = t>>3 (R0 multiples of 32 keep row&7 invariant).
    const int srow = t >> 3;
    const int scol = ((t & 7) ^ ((t >> 3) & 7)) * 8;   // bf16 units
    const u16* aS = A + (size_t)(brow + srow) * K + scol;
    const u16* bS = W + (size_t)(bcol + srow) * K + scol;
    char* dA = (char*)lds + t * 16;
    char* dB = (char*)lds + 32768 + t * 16;

    f32x16 acc[4][4] = {};

    // prologue: stage tile0 -> buf0; drain; barrier.
    STG_ALL(0, 0);
    VMW0();
    __builtin_amdgcn_s_barrier();
    CFENCE();

    for (int T = 0; T < NK; T += 2) {
        const bool more = (T + 2) < NK;
        TILE(0, STG_ALL(65536, T + 1), { VMW0(); });
        TILE(65536, { if (more) STG_ALL(0, T + 2); }, { if (more) VMW0(); });
    }

    // ---------------- epilogue: LDS transpose -> coalesced float4 stores ------
    // C/D (32x32): col = lane&31, row = (reg&3) + 8*(reg>>2) + 4*(lane>>5).
    // acc[m][n]: rows wm*128 + m*32.., cols wn*128 + n*32.. .
    float* Lf = (float*)lds;
    const int lrofs = (lane >> 5) * 4;
    const int cg = bcol + lane * 4;         // 4 output cols per lane

    float4 wpv[4];
    float bpv[4];
#pragma unroll
    for (int j = 0; j < 4; ++j) {
        wpv[j] = *(const float4*)&Wpos[(cg + j) * 4];
        bpv[j] = bpos[cg + j];
    }

#pragma unroll
    for (int mb = 0; mb < 4; ++mb) {
        __builtin_amdgcn_s_barrier();
        CFENCE();
#pragma unroll
        for (int nb = 0; nb < 4; ++nb) {
            const int cc = wn * 128 + nb * 32 + l31;
#pragma unroll
            for (int reg = 0; reg < 16; ++reg) {
                const int frow = (reg & 3) + 8 * (reg >> 2) + lrofs;
                Lf[(wm * 32 + frow) * 256 + cc] = acc[mb][nb][reg];
            }
        }
        __builtin_amdgcn_s_barrier();
        CFENCE();
#pragma unroll
        for (int i = 0; i < 16; ++i) {
            const int lrow = wid + 4 * i;                     // 0..63
            const int gr = brow + (lrow >> 5) * 128 + mb * 32 + (lrow & 31);
            const float4 v = *(const float4*)&Lf[lrow * 256 + lane * 4];
            const float4 bb = *(const float4*)&bbox[(size_t)gr * 4];
            float4 o;
            o.x = v.x + bpv[0] + bb.x * wpv[0].x + bb.y * wpv[0].y + bb.z * wpv[0].z + bb.w * wpv[0].w;
            o.y = v.y + bpv[1] + bb.x * wpv[1].x + bb.y * wpv[1].y + bb.z * wpv[1].z + bb.w * wpv[1].w;
            o.z = v.z + bpv[2] + bb.x * wpv[2].x + bb.y * wpv[2].y + bb.z * wpv[2].z + bb.w * wpv[2].w;
            o.w = v.w + bpv[3] + bb.x * wpv[3].x + bb.y * wpv[3].y + bb.z * wpv[3].z + bb.w * wpv[3].w;
            *(float4*)&out[(size_t)(gr + 1) * D + cg] = o;
        }
    }
}

// ---------------------------------------------------------------------------
extern "C" void kernel_launch(void* const* d_in, const int* in_sizes, int n_in,
                              void* d_out, int out_size, void* d_ws, size_t ws_size,
                              hipStream_t stream)
{
    const float* patches   = (const float*)d_in[0];
    const float* bbox      = (const float*)d_in[1];
    const float* ln1_w     = (const float*)d_in[2];
    const float* ln1_b     = (const float*)d_in[3];
    const float* W_patch   = (const float*)d_in[4];
    const float* class_emb = (const float*)d_in[5];
    const float* W_pos     = (const float*)d_in[6];
    const float* b_pos     = (const float*)d_in[7];
    const float* class_pos = (const float*)d_in[8];
    float* out = (float*)d_out;

    const int N = in_sizes[1] / 4;   // 16384
    const int K = in_sizes[2];       // 3072
    const int D = in_sizes[7];       // 1024

    u16* Abf = (u16*)d_ws;                       // [N,K] bf16
    u16* Wbf = Abf + (size_t)N * K;              // [D,K] bf16

    prep_kernel<<<N + D + 1, 256, 0, stream>>>(patches, ln1_w, ln1_b, W_patch,
                                               class_emb, class_pos, Abf, Wbf, out,
                                               N, D, K);

    const int nblk = (N / 256) * (D / 256);      // 64 * 4 = 256
    gemm_256_r15_kernel<<<nblk, 256, 0, stream>>>(Abf, Wbf, bbox, W_pos, b_pos, out, D);
}

// Round 16
// 158.774 us; speedup vs baseline: 1.4693x; 1.4693x over previous
//
#include <hip/hip_runtime.h>

typedef unsigned short u16;
typedef __attribute__((ext_vector_type(8))) short bf16x8;
typedef __attribute__((ext_vector_type(4))) float f32x4;

#define AS1C(p) ((const __attribute__((address_space(1))) void*)(p))
#define AS3(p)  ((__attribute__((address_space(3))) void*)(p))

// s_barrier is NOT a compiler memory fence; CFENCE pins LDS/global ops.
#define CFENCE() asm volatile("" ::: "memory")

__device__ __forceinline__ u16 f2bf(float f) {
    unsigned u = __float_as_uint(f);
    u += 0x7fffu + ((u >> 16) & 1u);   // RTNE
    return (u16)(u >> 16);
}

// ---------------------------------------------------------------------------
// Fused prep: blocks [0,N): LayerNorm row -> bf16 A.
//             blocks [N,N+D): cast W_patch row -> bf16 W.
//             block  N+D:     class_emb + class_pos -> out row 0.
// Measured at HBM roofline (~48us).
// ---------------------------------------------------------------------------
__global__ __launch_bounds__(256) void prep_kernel(
    const float* __restrict__ x, const float* __restrict__ w,
    const float* __restrict__ b, const float* __restrict__ Wp,
    const float* __restrict__ ce, const float* __restrict__ cp,
    u16* __restrict__ A, u16* __restrict__ Wb, float* __restrict__ out,
    int N, int D, int K)
{
    const int blk = blockIdx.x;
    const int t = threadIdx.x;

    if (blk < N) {
        const float* xr = x + (size_t)blk * K;
        float4 v[3];
#pragma unroll
        for (int i = 0; i < 3; ++i)
            v[i] = *(const float4*)&xr[(i * 256 + t) * 4];

        float s = 0.f;
#pragma unroll
        for (int i = 0; i < 3; ++i) s += v[i].x + v[i].y + v[i].z + v[i].w;
#pragma unroll
        for (int off = 32; off; off >>= 1) s += __shfl_down(s, off);

        __shared__ float red[8];
        const int wid = t >> 6, lane = t & 63;
        if (lane == 0) red[wid] = s;
        __syncthreads();
        const float mu = (red[0] + red[1] + red[2] + red[3]) * (1.0f / 3072.0f);

        float sq = 0.f;
#pragma unroll
        for (int i = 0; i < 3; ++i) {
            float dx = v[i].x - mu, dy = v[i].y - mu, dz = v[i].z - mu, dw = v[i].w - mu;
            sq += dx * dx + dy * dy + dz * dz + dw * dw;
        }
#pragma unroll
        for (int off = 32; off; off >>= 1) sq += __shfl_down(sq, off);
        if (lane == 0) red[4 + wid] = sq;
        __syncthreads();
        const float var = (red[4] + red[5] + red[6] + red[7]) * (1.0f / 3072.0f);
        const float inv = rsqrtf(var + 1e-5f);

#pragma unroll
        for (int i = 0; i < 3; ++i) {
            const int j = (i * 256 + t) * 4;
            const float4 wv = *(const float4*)&w[j];
            const float4 bv = *(const float4*)&b[j];
            ushort4 o;
            o.x = f2bf((v[i].x - mu) * inv * wv.x + bv.x);
            o.y = f2bf((v[i].y - mu) * inv * wv.y + bv.y);
            o.z = f2bf((v[i].z - mu) * inv * wv.z + bv.z);
            o.w = f2bf((v[i].w - mu) * inv * wv.w + bv.w);
            *(ushort4*)&A[(size_t)blk * K + j] = o;
        }
    } else if (blk < N + D) {
        const int row = blk - N;
        const float* wr = Wp + (size_t)row * K;
#pragma unroll
        for (int i = 0; i < 3; ++i) {
            const int j = (i * 256 + t) * 4;
            const float4 v = *(const float4*)&wr[j];
            ushort4 o;
            o.x = f2bf(v.x); o.y = f2bf(v.y); o.z = f2bf(v.z); o.w = f2bf(v.w);
            *(ushort4*)&Wb[(size_t)row * K + j] = o;
        }
    } else {
#pragma unroll
        for (int i = 0; i < 4; ++i) {
            const int j = i * 256 + t;
            out[j] = ce[j] + cp[j];
        }
    }
}

// ---------------------------------------------------------------------------
// 256x256 bf16 GEMM, mfma_f32_16x16x32_bf16, 8 waves (2Mx4N), wave 128x64.
// R16 = R12 (best: ladder lgkm + one end-barrier/phase + counted vmcnt)
// with the LDS swizzle REPLACED by m201's verified st_16x32:
//   stored byte = b ^ (((b>>9)&1)<<5)  i.e. col_bit5 ^= row_bit2.
// My 1-bit/3-bit row-XOR variants all measured exactly +4 cyc/ds_read_b128
// (SQ_LDS_BANK_CONFLICT = 4.0 x reads in R1..R15); m201's st_16x32 measures
// ~0.09/read on the same instruction mix -> this is the one verified-
// conflict-free formula. Read side: xorb = ((fr>>2)&1)<<5 (row bit2 = fr
// bit2 for all A/B fragment rows). Stage side: linear LDS dest, source col
// pre-swizzled scol = ((t&7)*8) ^ (((t>>5)&1)<<4) bf16 (row bit2 = (t>>5)&1,
// invariant across R0 since all R0 are multiples of 64 rows).
// ---------------------------------------------------------------------------
#define STG_A(BUFOFS, R0, T_) \
    __builtin_amdgcn_global_load_lds(AS1C(aS + (size_t)(R0) * 3072 + (T_) * 64), \
                                     AS3(dA + (BUFOFS) + (R0) * 128), 16, 0, 0)
#define STG_B(BUFOFS, R0, T_) \
    __builtin_amdgcn_global_load_lds(AS1C(bS + (size_t)(R0) * 3072 + (T_) * 64), \
                                     AS3(dB + (BUFOFS) + (R0) * 128), 16, 0, 0)

#define MFMA16(d, a, b) d = __builtin_amdgcn_mfma_f32_16x16x32_bf16(a, b, d, 0, 0, 0)

#define LGKM(N_) asm volatile("s_waitcnt lgkmcnt(" #N_ ")" ::: "memory"); \
                 __builtin_amdgcn_sched_barrier(0)

// Phase (MH, k-half KH on buffer BUF): 8 ds_read_b128 (B first), laddered
// lgkm waits, 16 MFMA16 in 4 groups, vmcnt publish, ONE end barrier.
#define PH16(BUF, MH, KH, STG, WT) do {                                           \
    const char* Ab = L + (BUF) + aRowBase + (MH) * 8192;                          \
    const char* Bb = L + (BUF) + bRowBase;                                        \
    const int ck = (KH) ? ckh1 : ckh0;                                            \
    bf16x8 b0 = *(const bf16x8*)(Bb + 0 * 2048 + ck);                             \
    bf16x8 b1 = *(const bf16x8*)(Bb + 1 * 2048 + ck);                             \
    bf16x8 b2 = *(const bf16x8*)(Bb + 2 * 2048 + ck);                             \
    bf16x8 b3 = *(const bf16x8*)(Bb + 3 * 2048 + ck);                             \
    bf16x8 a0 = *(const bf16x8*)(Ab + 0 * 2048 + ck);                             \
    bf16x8 a1 = *(const bf16x8*)(Ab + 1 * 2048 + ck);                             \
    bf16x8 a2 = *(const bf16x8*)(Ab + 2 * 2048 + ck);                             \
    bf16x8 a3 = *(const bf16x8*)(Ab + 3 * 2048 + ck);                             \
    STG;                                                                          \
    __builtin_amdgcn_s_setprio(1);                                                \
    LGKM(3);                                                                      \
    MFMA16(acc[(MH)*4+0][0], a0, b0); MFMA16(acc[(MH)*4+0][1], a0, b1);           \
    MFMA16(acc[(MH)*4+0][2], a0, b2); MFMA16(acc[(MH)*4+0][3], a0, b3);           \
    LGKM(2);                                                                      \
    MFMA16(acc[(MH)*4+1][0], a1, b0); MFMA16(acc[(MH)*4+1][1], a1, b1);           \
    MFMA16(acc[(MH)*4+1][2], a1, b2); MFMA16(acc[(MH)*4+1][3], a1, b3);           \
    LGKM(1);                                                                      \
    MFMA16(acc[(MH)*4+2][0], a2, b0); MFMA16(acc[(MH)*4+2][1], a2, b1);           \
    MFMA16(acc[(MH)*4+2][2], a2, b2); MFMA16(acc[(MH)*4+2][3], a2, b3);           \
    LGKM(0);                                                                      \
    MFMA16(acc[(MH)*4+3][0], a3, b0); MFMA16(acc[(MH)*4+3][1], a3, b1);           \
    MFMA16(acc[(MH)*4+3][2], a3, b2); MFMA16(acc[(MH)*4+3][3], a3, b3);           \
    __builtin_amdgcn_s_setprio(0);                                                \
    WT;                                                                           \
    __builtin_amdgcn_s_barrier();                                                 \
    CFENCE();                                                                     \
} while (0)

__global__ __launch_bounds__(512, 2) void gemm_256_st16_kernel(
    const u16* __restrict__ A, const u16* __restrict__ W,
    const float* __restrict__ bbox, const float* __restrict__ Wpos,
    const float* __restrict__ bpos, float* __restrict__ out,
    int D)
{
    __shared__ __align__(16) char lds[131072];
    const char* L = (const char*)lds;
    const int K = 3072;
    const int NK = 48;                     // K / 64

    // XCD-bijective swizzle: 256 blocks, 8 XCDs, 32 contiguous tiles per XCD.
    const int bid = blockIdx.x;
    const int swb = (bid & 7) * 32 + (bid >> 3);
    const int bx = swb & 3;                // D/256 = 4
    const int by = swb >> 2;               // M/256 = 64
    const int brow = by * 256;
    const int bcol = bx * 256;

    const int t = threadIdx.x;
    const int wid = t >> 6, lane = t & 63;
    const int wm = wid >> 2;               // 0..1
    const int wn = wid & 3;                // 0..3
    const int fr = lane & 15;
    const int kq16 = ((lane >> 4) & 3) * 16;   // 16B quarter within 64B k-half
    // st_16x32: col_bit5 ^= row_bit2; row bit2 == fr bit2 for all frag rows.
    const int xorb = ((fr >> 2) & 1) << 5;
    const int aRowBase = (wm * 128 + fr) * 128;
    const int bRowBase = 32768 + (wn * 64 + fr) * 128;
    const int ckh0 = (0  + kq16) ^ xorb;
    const int ckh1 = (64 + kq16) ^ xorb;

    // staging: linear LDS dest (t*16 B), pre-swizzled global source.
    // dest row = t>>3 (row bit2 = (t>>5)&1), dest col slot = t&7;
    // source col = dest col ^ (row_bit2 << 5) bytes.
    const int srow = t >> 3;
    const int scol = ((t & 7) * 8) ^ (((t >> 5) & 1) << 4);   // bf16 units
    const u16* aS = A + (size_t)(brow + srow) * K + scol;
    const u16* bS = W + (size_t)(bcol + srow) * K + scol;
    char* dA = (char*)lds + t * 16;
    char* dB = (char*)lds + 32768 + t * 16;

    f32x4 acc[8][4] = {};

    // prologue: tile0 full (8 STG) -> buf0; drain; barrier.
    STG_B(0, 0, 0);   STG_B(0, 64, 0);  STG_B(0, 128, 0); STG_B(0, 192, 0);
    STG_A(0, 0, 0);   STG_A(0, 128, 0); STG_A(0, 64, 0);  STG_A(0, 192, 0);
    asm volatile("s_waitcnt vmcnt(0)" ::: "memory");
    __builtin_amdgcn_s_barrier();
    CFENCE();

    for (int T = 0; T < NK; T += 2) {
        const bool more = (T + 2) < NK;
        // tile T in buf0
        PH16(0, 0, 0, { STG_B(65536, 0, T + 1); STG_B(65536, 64, T + 1); }, ((void)0));
        PH16(0, 0, 1, { STG_B(65536, 128, T + 1); STG_B(65536, 192, T + 1); },
             { asm volatile("s_waitcnt vmcnt(4)" ::: "memory"); });
        PH16(0, 1, 0, { STG_A(65536, 0, T + 1); STG_A(65536, 128, T + 1); }, ((void)0));
        PH16(0, 1, 1, { STG_A(65536, 64, T + 1); STG_A(65536, 192, T + 1); },
             { asm volatile("s_waitcnt vmcnt(2)" ::: "memory"); });
        // tile T+1 in buf1
        PH16(65536, 0, 0, { if (more) { STG_B(0, 0, T + 2); STG_B(0, 64, T + 2); } }, ((void)0));
        PH16(65536, 0, 1, { if (more) { STG_B(0, 128, T + 2); STG_B(0, 192, T + 2); } },
             { if (more) asm volatile("s_waitcnt vmcnt(4)" ::: "memory");
               else      asm volatile("s_waitcnt vmcnt(0)" ::: "memory"); });
        PH16(65536, 1, 0, { if (more) { STG_A(0, 0, T + 2); STG_A(0, 128, T + 2); } }, ((void)0));
        PH16(65536, 1, 1, { if (more) { STG_A(0, 64, T + 2); STG_A(0, 192, T + 2); } },
             { if (more) asm volatile("s_waitcnt vmcnt(2)" ::: "memory"); });
    }

    // ---------------- epilogue: LDS transpose -> coalesced float4 stores ------
    // 16x16 C/D layout: col = lane&15, row = (lane>>4)*4 + r.
    // acc[mi][n] covers rows wm*128 + mi*16 .. +16, cols wn*64 + n*16 .. +16.
    float* Lf = (float*)lds;
    const int r4 = ((lane >> 4) & 3) * 4;   // row sub-offset within fragment
    const int cg = bcol + lane * 4;         // 4 output cols per lane (coalesced)

    float4 wpv[4];
    float bpv[4];
#pragma unroll
    for (int j = 0; j < 4; ++j) {
        wpv[j] = *(const float4*)&Wpos[(cg + j) * 4];
        bpv[j] = bpos[cg + j];
    }

#pragma unroll
    for (int c = 0; c < 4; ++c) {           // chunk c: block rows {c*32..+32} u {128+c*32..+32}
        __builtin_amdgcn_s_barrier();
        CFENCE();
#pragma unroll
        for (int q = 0; q < 2; ++q) {       // frag mi = c*2+q
#pragma unroll
            for (int n = 0; n < 4; ++n) {
                const f32x4 v = acc[c * 2 + q][n];
                const int col = wn * 64 + n * 16 + fr;
#pragma unroll
                for (int r = 0; r < 4; ++r)
                    Lf[(wm * 32 + q * 16 + r4 + r) * 256 + col] = v[r];
            }
        }
        __builtin_amdgcn_s_barrier();
        CFENCE();
#pragma unroll
        for (int i = 0; i < 8; ++i) {
            const int lrow = wid + 8 * i;                     // 0..63
            const int gr = brow + (lrow >> 5) * 128 + c * 32 + (lrow & 31);
            const float4 v = *(const float4*)&Lf[lrow * 256 + lane * 4];
            const float4 bb = *(const float4*)&bbox[(size_t)gr * 4];
            float4 o;
            o.x = v.x + bpv[0] + bb.x * wpv[0].x + bb.y * wpv[0].y + bb.z * wpv[0].z + bb.w * wpv[0].w;
            o.y = v.y + bpv[1] + bb.x * wpv[1].x + bb.y * wpv[1].y + bb.z * wpv[1].z + bb.w * wpv[1].w;
            o.z = v.z + bpv[2] + bb.x * wpv[2].x + bb.y * wpv[2].y + bb.z * wpv[2].z + bb.w * wpv[2].w;
            o.w = v.w + bpv[3] + bb.x * wpv[3].x + bb.y * wpv[3].y + bb.z * wpv[3].z + bb.w * wpv[3].w;
            *(float4*)&out[(size_t)(gr + 1) * D + cg] = o;
        }
    }
}

// ---------------------------------------------------------------------------
extern "C" void kernel_launch(void* const* d_in, const int* in_sizes, int n_in,
                              void* d_out, int out_size, void* d_ws, size_t ws_size,
                              hipStream_t stream)
{
    const float* patches   = (const float*)d_in[0];
    const float* bbox      = (const float*)d_in[1];
    const float* ln1_w     = (const float*)d_in[2];
    const float* ln1_b     = (const float*)d_in[3];
    const float* W_patch   = (const float*)d_in[4];
    const float* class_emb = (const float*)d_in[5];
    const float* W_pos     = (const float*)d_in[6];
    const float* b_pos     = (const float*)d_in[7];
    const float* class_pos = (const float*)d_in[8];
    float* out = (float*)d_out;

    const int N = in_sizes[1] / 4;   // 16384
    const int K = in_sizes[2];       // 3072
    const int D = in_sizes[7];       // 1024

    u16* Abf = (u16*)d_ws;                       // [N,K] bf16
    u16* Wbf = Abf + (size_t)N * K;              // [D,K] bf16

    prep_kernel<<<N + D + 1, 256, 0, stream>>>(patches, ln1_w, ln1_b, W_patch,
                                               class_emb, class_pos, Abf, Wbf, out,
                                               N, D, K);

    const int nblk = (N / 256) * (D / 256);      // 64 * 4 = 256
    gemm_256_st16_kernel<<<nblk, 512, 0, stream>>>(Abf, Wbf, bbox, W_pos, b_pos, out, D);
}

// Round 18
// 149.675 us; speedup vs baseline: 1.5587x; 1.0608x over previous
//
#include <hip/hip_runtime.h>

typedef unsigned short u16;
typedef __attribute__((ext_vector_type(8))) short bf16x8;
typedef __attribute__((ext_vector_type(4))) float f32x4;

#define AS1C(p) ((const __attribute__((address_space(1))) void*)(p))
#define AS3(p)  ((__attribute__((address_space(3))) void*)(p))

// s_barrier is NOT a compiler memory fence; CFENCE pins LDS/global ops.
#define CFENCE() asm volatile("" ::: "memory")

__device__ __forceinline__ u16 f2bf(float f) {
    unsigned u = __float_as_uint(f);
    u += 0x7fffu + ((u >> 16) & 1u);   // RTNE
    return (u16)(u >> 16);
}

// ---------------------------------------------------------------------------
// Fused prep: blocks [0,N): LayerNorm row -> bf16 A.
//             blocks [N,N+D): cast W_patch row -> bf16 W.
//             block  N+D:     class_emb + class_pos -> out row 0.
// Measured at HBM roofline (~48us).
// ---------------------------------------------------------------------------
__global__ __launch_bounds__(256) void prep_kernel(
    const float* __restrict__ x, const float* __restrict__ w,
    const float* __restrict__ b, const float* __restrict__ Wp,
    const float* __restrict__ ce, const float* __restrict__ cp,
    u16* __restrict__ A, u16* __restrict__ Wb, float* __restrict__ out,
    int N, int D, int K)
{
    const int blk = blockIdx.x;
    const int t = threadIdx.x;

    if (blk < N) {
        const float* xr = x + (size_t)blk * K;
        float4 v[3];
#pragma unroll
        for (int i = 0; i < 3; ++i)
            v[i] = *(const float4*)&xr[(i * 256 + t) * 4];

        float s = 0.f;
#pragma unroll
        for (int i = 0; i < 3; ++i) s += v[i].x + v[i].y + v[i].z + v[i].w;
#pragma unroll
        for (int off = 32; off; off >>= 1) s += __shfl_down(s, off);

        __shared__ float red[8];
        const int wid = t >> 6, lane = t & 63;
        if (lane == 0) red[wid] = s;
        __syncthreads();
        const float mu = (red[0] + red[1] + red[2] + red[3]) * (1.0f / 3072.0f);

        float sq = 0.f;
#pragma unroll
        for (int i = 0; i < 3; ++i) {
            float dx = v[i].x - mu, dy = v[i].y - mu, dz = v[i].z - mu, dw = v[i].w - mu;
            sq += dx * dx + dy * dy + dz * dz + dw * dw;
        }
#pragma unroll
        for (int off = 32; off; off >>= 1) sq += __shfl_down(sq, off);
        if (lane == 0) red[4 + wid] = sq;
        __syncthreads();
        const float var = (red[4] + red[5] + red[6] + red[7]) * (1.0f / 3072.0f);
        const float inv = rsqrtf(var + 1e-5f);

#pragma unroll
        for (int i = 0; i < 3; ++i) {
            const int j = (i * 256 + t) * 4;
            const float4 wv = *(const float4*)&w[j];
            const float4 bv = *(const float4*)&b[j];
            ushort4 o;
            o.x = f2bf((v[i].x - mu) * inv * wv.x + bv.x);
            o.y = f2bf((v[i].y - mu) * inv * wv.y + bv.y);
            o.z = f2bf((v[i].z - mu) * inv * wv.z + bv.z);
            o.w = f2bf((v[i].w - mu) * inv * wv.w + bv.w);
            *(ushort4*)&A[(size_t)blk * K + j] = o;
        }
    } else if (blk < N + D) {
        const int row = blk - N;
        const float* wr = Wp + (size_t)row * K;
#pragma unroll
        for (int i = 0; i < 3; ++i) {
            const int j = (i * 256 + t) * 4;
            const float4 v = *(const float4*)&wr[j];
            ushort4 o;
            o.x = f2bf(v.x); o.y = f2bf(v.y); o.z = f2bf(v.z); o.w = f2bf(v.w);
            *(ushort4*)&Wb[(size_t)row * K + j] = o;
        }
    } else {
#pragma unroll
        for (int i = 0; i < 4; ++i) {
            const int j = i * 256 + t;
            out[j] = ce[j] + cp[j];
        }
    }
}

// ---------------------------------------------------------------------------
// 256x256 bf16 GEMM, mfma_f32_16x16x32_bf16, 8 waves (2Mx4N), wave 128x64.
// R18 = R17's B-fragment reuse (phases (mh0,kh)/(mh1,kh) share B; 48 LDS
// reads/tile/wave vs R12's 64) with the publish ledger RE-DERIVED for the
// new read order (R17's race: A-MH1 was read at Ph2/Ph6 but only published
// at the END of those phases). Per-iteration ledger (outstanding counts
// verified phase by phase; every wait covers loads >=1 phase old):
//   Ph1(B+A0,ck0,buf0): stage B(T+1)lo  | vmcnt(2) -> drains A-MH1(T)
//   Ph2(A1,ck0):        stage B(T+1)hi  |
//   Ph3(B+A0,ck1):      stage A(T+1)MH0 |
//   Ph4(A1,ck1):        stage A(T+1)MH1 | vmcnt(2) -> drains B+A-MH0(T+1)
//   Ph5(B+A0,ck0,buf1): stage B(T+2)lo  | vmcnt(2) -> drains A-MH1(T+1)
//                                         [tail: vmcnt(0)]
//   Ph6(A1,ck0):        stage B(T+2)hi  |
//   Ph7(B+A0,ck1):      stage A(T+2)MH0 |
//   Ph8(A1,ck1):        stage A(T+2)MH1 | vmcnt(2) -> drains B+A-MH0(T+2)
// ---------------------------------------------------------------------------
#define STG_A(BUFOFS, R0, T_) \
    __builtin_amdgcn_global_load_lds(AS1C(aS + (size_t)(R0) * 3072 + (T_) * 64), \
                                     AS3(dA + (BUFOFS) + (R0) * 128), 16, 0, 0)
#define STG_B(BUFOFS, R0, T_) \
    __builtin_amdgcn_global_load_lds(AS1C(bS + (size_t)(R0) * 3072 + (T_) * 64), \
                                     AS3(dB + (BUFOFS) + (R0) * 128), 16, 0, 0)

#define MFMA16(d, a, b) d = __builtin_amdgcn_mfma_f32_16x16x32_bf16(a, b, d, 0, 0, 0)

#define LGKM(N_) asm volatile("s_waitcnt lgkmcnt(" #N_ ")" ::: "memory"); \
                 __builtin_amdgcn_sched_barrier(0)

// MFMA block for M-half MH using held B-frags hb0..hb3 and A-frags a0..a3.
#define MFMA_LADDER(MH, a0, a1, a2, a3)                                           \
    LGKM(3);                                                                      \
    MFMA16(acc[(MH)*4+0][0], a0, hb0); MFMA16(acc[(MH)*4+0][1], a0, hb1);         \
    MFMA16(acc[(MH)*4+0][2], a0, hb2); MFMA16(acc[(MH)*4+0][3], a0, hb3);         \
    LGKM(2);                                                                      \
    MFMA16(acc[(MH)*4+1][0], a1, hb0); MFMA16(acc[(MH)*4+1][1], a1, hb1);         \
    MFMA16(acc[(MH)*4+1][2], a1, hb2); MFMA16(acc[(MH)*4+1][3], a1, hb3);         \
    LGKM(1);                                                                      \
    MFMA16(acc[(MH)*4+2][0], a2, hb0); MFMA16(acc[(MH)*4+2][1], a2, hb1);         \
    MFMA16(acc[(MH)*4+2][2], a2, hb2); MFMA16(acc[(MH)*4+2][3], a2, hb3);         \
    LGKM(0);                                                                      \
    MFMA16(acc[(MH)*4+3][0], a3, hb0); MFMA16(acc[(MH)*4+3][1], a3, hb1);         \
    MFMA16(acc[(MH)*4+3][2], a3, hb2); MFMA16(acc[(MH)*4+3][3], a3, hb3)

// Phase mh0: read 4 B-frags (-> held regs) + 4 A-frags (8 reads), MFMA mh0.
#define PHB(BUF, KH, STG, WT) do {                                                \
    const char* Ab = L + (BUF) + aRowBase;                                        \
    const char* Bb = L + (BUF) + bRowBase;                                        \
    const int ck = (KH) ? ckh1 : ckh0;                                            \
    hb0 = *(const bf16x8*)(Bb + 0 * 2048 + ck);                                   \
    hb1 = *(const bf16x8*)(Bb + 1 * 2048 + ck);                                   \
    hb2 = *(const bf16x8*)(Bb + 2 * 2048 + ck);                                   \
    hb3 = *(const bf16x8*)(Bb + 3 * 2048 + ck);                                   \
    bf16x8 a0 = *(const bf16x8*)(Ab + 0 * 2048 + ck);                             \
    bf16x8 a1 = *(const bf16x8*)(Ab + 1 * 2048 + ck);                             \
    bf16x8 a2 = *(const bf16x8*)(Ab + 2 * 2048 + ck);                             \
    bf16x8 a3 = *(const bf16x8*)(Ab + 3 * 2048 + ck);                             \
    STG;                                                                          \
    __builtin_amdgcn_s_setprio(1);                                                \
    MFMA_LADDER(0, a0, a1, a2, a3);                                               \
    __builtin_amdgcn_s_setprio(0);                                                \
    WT;                                                                           \
    __builtin_amdgcn_s_barrier();                                                 \
    CFENCE();                                                                     \
} while (0)

// Phase mh1: B held in regs from the paired PHB; read only 4 A-frags.
#define PHA(BUF, KH, STG, WT) do {                                                \
    const char* Ab = L + (BUF) + aRowBase + 8192;                                 \
    const int ck = (KH) ? ckh1 : ckh0;                                            \
    bf16x8 a0 = *(const bf16x8*)(Ab + 0 * 2048 + ck);                             \
    bf16x8 a1 = *(const bf16x8*)(Ab + 1 * 2048 + ck);                             \
    bf16x8 a2 = *(const bf16x8*)(Ab + 2 * 2048 + ck);                             \
    bf16x8 a3 = *(const bf16x8*)(Ab + 3 * 2048 + ck);                             \
    STG;                                                                          \
    __builtin_amdgcn_s_setprio(1);                                                \
    MFMA_LADDER(1, a0, a1, a2, a3);                                               \
    __builtin_amdgcn_s_setprio(0);                                                \
    WT;                                                                           \
    __builtin_amdgcn_s_barrier();                                                 \
    CFENCE();                                                                     \
} while (0)

__global__ __launch_bounds__(512, 2) void gemm_256_br2_kernel(
    const u16* __restrict__ A, const u16* __restrict__ W,
    const float* __restrict__ bbox, const float* __restrict__ Wpos,
    const float* __restrict__ bpos, float* __restrict__ out,
    int D)
{
    __shared__ __align__(16) char lds[131072];
    const char* L = (const char*)lds;
    const int K = 3072;
    const int NK = 48;                     // K / 64

    // XCD-bijective swizzle: 256 blocks, 8 XCDs, 32 contiguous tiles per XCD.
    const int bid = blockIdx.x;
    const int swb = (bid & 7) * 32 + (bid >> 3);
    const int bx = swb & 3;                // D/256 = 4
    const int by = swb >> 2;               // M/256 = 64
    const int brow = by * 256;
    const int bcol = bx * 256;

    const int t = threadIdx.x;
    const int wid = t >> 6, lane = t & 63;
    const int wm = wid >> 2;               // 0..1
    const int wn = wid & 3;                // 0..3
    const int fr = lane & 15;
    const int kq16 = ((lane >> 4) & 3) * 16;   // 16B quarter within 64B k-half
    const int xorb = (fr & 7) << 4;            // byte ^= (row&7)<<4
    const int aRowBase = (wm * 128 + fr) * 128;
    const int bRowBase = 32768 + (wn * 64 + fr) * 128;
    const int ckh0 = (0  + kq16) ^ xorb;
    const int ckh1 = (64 + kq16) ^ xorb;

    // staging: linear LDS dest (t*16 B), pre-swizzled global source.
    const int srow = t >> 3;
    const int scol = ((t & 7) ^ ((t >> 3) & 7)) * 8;   // bf16 units
    const u16* aS = A + (size_t)(brow + srow) * K + scol;
    const u16* bS = W + (size_t)(bcol + srow) * K + scol;
    char* dA = (char*)lds + t * 16;
    char* dB = (char*)lds + 32768 + t * 16;

    f32x4 acc[8][4] = {};
    bf16x8 hb0, hb1, hb2, hb3;             // held B-frags (shared mh0/mh1)

    // prologue: tile0 full (8 STG) -> buf0; drain; barrier.
    STG_B(0, 0, 0);   STG_B(0, 64, 0);  STG_B(0, 128, 0); STG_B(0, 192, 0);
    STG_A(0, 0, 0);   STG_A(0, 128, 0); STG_A(0, 64, 0);  STG_A(0, 192, 0);
    asm volatile("s_waitcnt vmcnt(0)" ::: "memory");
    __builtin_amdgcn_s_barrier();
    CFENCE();

    for (int T = 0; T < NK; T += 2) {
        const bool more = (T + 2) < NK;
        // tile T in buf0
        PHB(0, 0, { STG_B(65536, 0, T + 1); STG_B(65536, 64, T + 1); },
            { asm volatile("s_waitcnt vmcnt(2)" ::: "memory"); });       // Ph1
        PHA(0, 0, { STG_B(65536, 128, T + 1); STG_B(65536, 192, T + 1); },
            ((void)0));                                                  // Ph2
        PHB(0, 1, { STG_A(65536, 0, T + 1); STG_A(65536, 128, T + 1); },
            ((void)0));                                                  // Ph3
        PHA(0, 1, { STG_A(65536, 64, T + 1); STG_A(65536, 192, T + 1); },
            { asm volatile("s_waitcnt vmcnt(2)" ::: "memory"); });       // Ph4
        // tile T+1 in buf1
        PHB(65536, 0, { if (more) { STG_B(0, 0, T + 2); STG_B(0, 64, T + 2); } },
            { if (more) asm volatile("s_waitcnt vmcnt(2)" ::: "memory");
              else      asm volatile("s_waitcnt vmcnt(0)" ::: "memory"); }); // Ph5
        PHA(65536, 0, { if (more) { STG_B(0, 128, T + 2); STG_B(0, 192, T + 2); } },
            ((void)0));                                                  // Ph6
        PHB(65536, 1, { if (more) { STG_A(0, 0, T + 2); STG_A(0, 128, T + 2); } },
            ((void)0));                                                  // Ph7
        PHA(65536, 1, { if (more) { STG_A(0, 64, T + 2); STG_A(0, 192, T + 2); } },
            { if (more) asm volatile("s_waitcnt vmcnt(2)" ::: "memory"); }); // Ph8
    }

    // ---------------- epilogue: LDS transpose -> coalesced float4 stores ------
    // 16x16 C/D layout: col = lane&15, row = (lane>>4)*4 + r.
    // acc[mi][n] covers rows wm*128 + mi*16 .. +16, cols wn*64 + n*16 .. +16.
    float* Lf = (float*)lds;
    const int r4 = ((lane >> 4) & 3) * 4;   // row sub-offset within fragment
    const int cg = bcol + lane * 4;         // 4 output cols per lane (coalesced)

    float4 wpv[4];
    float bpv[4];
#pragma unroll
    for (int j = 0; j < 4; ++j) {
        wpv[j] = *(const float4*)&Wpos[(cg + j) * 4];
        bpv[j] = bpos[cg + j];
    }

#pragma unroll
    for (int c = 0; c < 4; ++c) {           // chunk c: block rows {c*32..+32} u {128+c*32..+32}
        __builtin_amdgcn_s_barrier();
        CFENCE();
#pragma unroll
        for (int q = 0; q < 2; ++q) {       // frag mi = c*2+q
#pragma unroll
            for (int n = 0; n < 4; ++n) {
                const f32x4 v = acc[c * 2 + q][n];
                const int col = wn * 64 + n * 16 + fr;
#pragma unroll
                for (int r = 0; r < 4; ++r)
                    Lf[(wm * 32 + q * 16 + r4 + r) * 256 + col] = v[r];
            }
        }
        __builtin_amdgcn_s_barrier();
        CFENCE();
#pragma unroll
        for (int i = 0; i < 8; ++i) {
            const int lrow = wid + 8 * i;                     // 0..63
            const int gr = brow + (lrow >> 5) * 128 + c * 32 + (lrow & 31);
            const float4 v = *(const float4*)&Lf[lrow * 256 + lane * 4];
            const float4 bb = *(const float4*)&bbox[(size_t)gr * 4];
            float4 o;
            o.x = v.x + bpv[0] + bb.x * wpv[0].x + bb.y * wpv[0].y + bb.z * wpv[0].z + bb.w * wpv[0].w;
            o.y = v.y + bpv[1] + bb.x * wpv[1].x + bb.y * wpv[1].y + bb.z * wpv[1].z + bb.w * wpv[1].w;
            o.z = v.z + bpv[2] + bb.x * wpv[2].x + bb.y * wpv[2].y + bb.z * wpv[2].z + bb.w * wpv[2].w;
            o.w = v.w + bpv[3] + bb.x * wpv[3].x + bb.y * wpv[3].y + bb.z * wpv[3].z + bb.w * wpv[3].w;
            *(float4*)&out[(size_t)(gr + 1) * D + cg] = o;
        }
    }
}

// ---------------------------------------------------------------------------
extern "C" void kernel_launch(void* const* d_in, const int* in_sizes, int n_in,
                              void* d_out, int out_size, void* d_ws, size_t ws_size,
                              hipStream_t stream)
{
    const float* patches   = (const float*)d_in[0];
    const float* bbox      = (const float*)d_in[1];
    const float* ln1_w     = (const float*)d_in[2];
    const float* ln1_b     = (const float*)d_in[3];
    const float* W_patch   = (const float*)d_in[4];
    const float* class_emb = (const float*)d_in[5];
    const float* W_pos     = (const float*)d_in[6];
    const float* b_pos     = (const float*)d_in[7];
    const float* class_pos = (const float*)d_in[8];
    float* out = (float*)d_out;

    const int N = in_sizes[1] / 4;   // 16384
    const int K = in_sizes[2];       // 3072
    const int D = in_sizes[7];       // 1024

    u16* Abf = (u16*)d_ws;                       // [N,K] bf16
    u16* Wbf = Abf + (size_t)N * K;              // [D,K] bf16

    prep_kernel<<<N + D + 1, 256, 0, stream>>>(patches, ln1_w, ln1_b, W_patch,
                                               class_emb, class_pos, Abf, Wbf, out,
                                               N, D, K);

    const int nblk = (N / 256) * (D / 256);      // 64 * 4 = 256
    gemm_256_br2_kernel<<<nblk, 512, 0, stream>>>(Abf, Wbf, bbox, W_pos, b_pos, out, D);
}